// Round 1
// baseline (1900.980 us; speedup 1.0000x reference)
//
#include <hip/hip_runtime.h>
#include <hip/hip_bf16.h>

#define B_ 2048
#define S_ 71
#define D_ 768
#define H_ 4
#define DH_ 192
#define TD_ 2304            // 3*D
#define M_ (B_ * S_)        // 145408 = 128*1136
#define TEXT_ 35

typedef unsigned short u16;
typedef unsigned int u32;
typedef __attribute__((ext_vector_type(4))) float f32x4;
typedef __attribute__((ext_vector_type(8))) short bf16x8;

__device__ __forceinline__ u16 f2bf(float f) {
  u32 u = __float_as_uint(f);
  u32 r = (u + 0x7FFFu + ((u >> 16) & 1u)) >> 16;  // RNE
  return (u16)r;
}
__device__ __forceinline__ float bf2f(u16 x) {
  return __uint_as_float(((u32)x) << 16);
}

// ---------------------------------------------------------------------------
// w_out [e][d] -> w_outT [d][e]  (768x768 fp32, tiny)
__global__ void k_transpose768(const float* __restrict__ in, float* __restrict__ out) {
  int idx = blockIdx.x * 256 + threadIdx.x;   // 589824 total, grid covers exactly
  int e = idx / 768, d = idx % 768;
  out[(size_t)d * 768 + e] = in[idx];
}

// ---------------------------------------------------------------------------
// GEMM: C[M,2304] = A[M,768] * w_qkv^T, bias + phi(elu+1 on q,k cols) epilogue.
// A is fp32 features (converted to bf16 during staging). B operand is w_qkv
// fp32 [2304,768] row-major == B^T layout [n][k] -> no transpose needed.
// 128x128 tile, BK=64, 4 waves (each 64x64 = 4x4 frags of 16x16x32 MFMA).
#define BK 64
#define LDP 72   // padded LDS stride (bf16 elems): 144B rows -> benign conflicts

__global__ __launch_bounds__(256) void k_gemm_qkv(
    const float* __restrict__ A,    // [M_,768] fp32
    const float* __restrict__ Bw,   // [2304,768] fp32 (n-major)
    const float* __restrict__ bias, // [2304]
    u16* __restrict__ C)            // [M_,2304] bf16, phi applied to cols<1536
{
  __shared__ u16 As[128 * LDP];
  __shared__ u16 Bs[128 * LDP];
  int t = threadIdx.x;
  int bn = blockIdx.x, bm = blockIdx.y;
  int lane = t & 63, wid = t >> 6;
  int wm = (wid >> 1) * 64, wn = (wid & 1) * 64;
  int lr = lane & 15;
  int lk = (lane >> 4) * 8;

  f32x4 acc[4][4] = {};
  const size_t arow0 = (size_t)bm * 128;
  const size_t brow0 = (size_t)bn * 128;

  for (int kt = 0; kt < 768; kt += BK) {
    __syncthreads();
    // stage A,B tiles: 1024 chunks of 8 elems each (fp32->bf16 on the fly)
#pragma unroll
    for (int i = 0; i < 4; ++i) {
      int idx = i * 256 + t;
      int row = idx >> 3, ks = (idx & 7) * 8;
      const float4* pa = (const float4*)(&A[(arow0 + row) * 768 + kt + ks]);
      float4 a0 = pa[0], a1 = pa[1];
      uint4 oa;
      oa.x = (u32)f2bf(a0.x) | ((u32)f2bf(a0.y) << 16);
      oa.y = (u32)f2bf(a0.z) | ((u32)f2bf(a0.w) << 16);
      oa.z = (u32)f2bf(a1.x) | ((u32)f2bf(a1.y) << 16);
      oa.w = (u32)f2bf(a1.z) | ((u32)f2bf(a1.w) << 16);
      *(uint4*)(&As[row * LDP + ks]) = oa;
      const float4* pb = (const float4*)(&Bw[(brow0 + row) * 768 + kt + ks]);
      float4 b0 = pb[0], b1 = pb[1];
      uint4 ob;
      ob.x = (u32)f2bf(b0.x) | ((u32)f2bf(b0.y) << 16);
      ob.y = (u32)f2bf(b0.z) | ((u32)f2bf(b0.w) << 16);
      ob.z = (u32)f2bf(b1.x) | ((u32)f2bf(b1.y) << 16);
      ob.w = (u32)f2bf(b1.z) | ((u32)f2bf(b1.w) << 16);
      *(uint4*)(&Bs[row * LDP + ks]) = ob;
    }
    __syncthreads();
#pragma unroll
    for (int kk = 0; kk < BK; kk += 32) {
      bf16x8 af[4], bf_[4];
#pragma unroll
      for (int m = 0; m < 4; ++m)
        af[m] = *(const bf16x8*)(&As[(wm + m * 16 + lr) * LDP + kk + lk]);
#pragma unroll
      for (int n = 0; n < 4; ++n)
        bf_[n] = *(const bf16x8*)(&Bs[(wn + n * 16 + lr) * LDP + kk + lk]);
#pragma unroll
      for (int m = 0; m < 4; ++m)
#pragma unroll
        for (int n = 0; n < 4; ++n)
          acc[m][n] = __builtin_amdgcn_mfma_f32_16x16x32_bf16(af[m], bf_[n], acc[m][n], 0, 0, 0);
    }
  }
  // epilogue: bias + phi on q/k columns, store bf16
  int rbase = (lane >> 4) * 4;
#pragma unroll
  for (int m = 0; m < 4; ++m) {
#pragma unroll
    for (int n = 0; n < 4; ++n) {
      int col = (int)brow0 + wn + n * 16 + lr;
      float bb = bias[col];
#pragma unroll
      for (int i = 0; i < 4; ++i) {
        size_t row = arow0 + wm + m * 16 + rbase + i;
        float v = acc[m][n][i] + bb;
        if (col < 1536) v = (v > 0.0f) ? (v + 1.0f) : __expf(v);
        C[row * TD_ + col] = f2bf(v);
      }
    }
  }
}

// ---------------------------------------------------------------------------
// Attention core, one block per (b,h). Never materializes kv[192][192]:
//   z[d]   = sum_s k[s,d]
//   den[s] = q[s,:].z + eps ; wt[s]=1/(35 den) (s<35), wi[s]=1/(36 den) (s>=35)
//   qt[d]  = sum_s q[s,d] wt[s] ; qi likewise
//   a_t[s] = k[s,:].qt ; a_i likewise   (sum over ALL s)
//   m_t[e] = sum_s a_t[s] v[s,e] ; m_i likewise
#define ALD 196  // LDS stride for 192-wide bf16 rows

__global__ __launch_bounds__(256) void k_attn(
    const u16* __restrict__ qkv,  // [M_,2304] bf16
    float* __restrict__ mt, float* __restrict__ mi)  // [B_,768] fp32
{
  __shared__ u16 qs[S_ * ALD];
  __shared__ u16 ks2[S_ * ALD];
  __shared__ float z[DH_], wt[S_], wi[S_], qt[DH_], qi[DH_], at[S_], ai[S_];
  int t = threadIdx.x;
  int b = blockIdx.x >> 2, h = blockIdx.x & 3;
  size_t base = (size_t)b * S_ * TD_;
  int qoff = h * DH_, koff = 768 + h * DH_, voff = 1536 + h * DH_;

  for (int idx = t; idx < S_ * 48; idx += 256) {
    int s = idx / 48, c = (idx % 48) * 4;
    *(ushort4*)(&qs[s * ALD + c])  = *(const ushort4*)(&qkv[base + (size_t)s * TD_ + qoff + c]);
    *(ushort4*)(&ks2[s * ALD + c]) = *(const ushort4*)(&qkv[base + (size_t)s * TD_ + koff + c]);
  }
  __syncthreads();
  if (t < DH_) {
    float a = 0;
    for (int s = 0; s < S_; ++s) a += bf2f(ks2[s * ALD + t]);
    z[t] = a;
  }
  __syncthreads();
  if (t < S_) {
    float a = 0;
    for (int d = 0; d < DH_; ++d) a += bf2f(qs[t * ALD + d]) * z[d];
    float den = a + 1e-6f;
    wt[t] = (t < TEXT_) ? 1.0f / (35.0f * den) : 0.0f;
    wi[t] = (t >= TEXT_) ? 1.0f / (36.0f * den) : 0.0f;
  }
  __syncthreads();
  if (t < DH_) {
    float aT = 0, aI = 0;
    for (int s = 0; s < S_; ++s) {
      float qv = bf2f(qs[s * ALD + t]);
      aT += qv * wt[s]; aI += qv * wi[s];
    }
    qt[t] = aT; qi[t] = aI;
  }
  __syncthreads();
  if (t < S_) {
    float aT = 0, aI = 0;
    for (int d = 0; d < DH_; ++d) {
      float kv = bf2f(ks2[t * ALD + d]);
      aT += kv * qt[d]; aI += kv * qi[d];
    }
    at[t] = aT; ai[t] = aI;
  }
  __syncthreads();
  if (t < DH_) {
    float aT = 0, aI = 0;
    for (int s = 0; s < S_; ++s) {
      float vv = bf2f(qkv[base + (size_t)s * TD_ + voff + t]);
      aT += at[s] * vv; aI += ai[s] * vv;
    }
    mt[(size_t)b * D_ + qoff + t] = aT;
    mi[(size_t)b * D_ + qoff + t] = aI;
  }
}

// ---------------------------------------------------------------------------
// Final head: f = m @ w_out^T + b_out ; r = tanh(f) ; cosine similarity.
// One block per batch element.
__global__ __launch_bounds__(256) void k_final(
    const float* __restrict__ mt, const float* __restrict__ mi,
    const float* __restrict__ wT,   // [768,768] = w_out transposed [d][e]
    const float* __restrict__ bout, // [768]
    float* __restrict__ out)        // [B_]
{
  __shared__ float mts[768], mis[768];
  __shared__ float red[3][4];
  int t = threadIdx.x, b = blockIdx.x;
  for (int i = t; i < 768; i += 256) {
    mts[i] = mt[(size_t)b * 768 + i];
    mis[i] = mi[(size_t)b * 768 + i];
  }
  __syncthreads();
  float aT[3] = {0, 0, 0}, aI[3] = {0, 0, 0};
  for (int d = 0; d < 768; ++d) {
    float m1 = mts[d], m2 = mis[d];
    const float* wrow = wT + (size_t)d * 768 + t;
#pragma unroll
    for (int j = 0; j < 3; ++j) {
      float w = wrow[j * 256];
      aT[j] += m1 * w; aI[j] += m2 * w;
    }
  }
  float st = 0, si = 0, sd = 0;
#pragma unroll
  for (int j = 0; j < 3; ++j) {
    float bo = bout[t + j * 256];
    float rt = tanhf(aT[j] + bo);
    float ri = tanhf(aI[j] + bo);
    st += rt * rt; si += ri * ri; sd += rt * ri;
  }
#pragma unroll
  for (int off = 32; off >= 1; off >>= 1) {
    st += __shfl_down(st, off);
    si += __shfl_down(si, off);
    sd += __shfl_down(sd, off);
  }
  int lane = t & 63, wid = t >> 6;
  if (lane == 0) { red[0][wid] = st; red[1][wid] = si; red[2][wid] = sd; }
  __syncthreads();
  if (t == 0) {
    float S1 = red[0][0] + red[0][1] + red[0][2] + red[0][3];
    float S2 = red[1][0] + red[1][1] + red[1][2] + red[1][3];
    float S3 = red[2][0] + red[2][1] + red[2][2] + red[2][3];
    out[b] = S3 / (fmaxf(sqrtf(S1), 1e-8f) * fmaxf(sqrtf(S2), 1e-8f));
  }
}

// ---------------------------------------------------------------------------
extern "C" void kernel_launch(void* const* d_in, const int* in_sizes, int n_in,
                              void* d_out, int out_size, void* d_ws, size_t ws_size,
                              hipStream_t stream) {
  const float* features = (const float*)d_in[0];
  // d_in[1] = attention_mask (unused by forward)
  const float* w_qkv = (const float*)d_in[2];
  const float* b_qkv = (const float*)d_in[3];
  const float* w_out = (const float*)d_in[4];
  const float* b_out = (const float*)d_in[5];
  float* out = (float*)d_out;

  char* ws = (char*)d_ws;
  size_t off = 0;
  auto alloc = [&](size_t bytes) {
    void* p = ws + off;
    off += (bytes + 255) & ~(size_t)255;
    return p;
  };
  u16* qkv  = (u16*)alloc((size_t)M_ * TD_ * 2);   // 670 MB
  float* wT = (float*)alloc((size_t)D_ * D_ * 4);  // 2.4 MB
  float* mt = (float*)alloc((size_t)B_ * D_ * 4);  // 6.3 MB
  float* mi = (float*)alloc((size_t)B_ * D_ * 4);  // 6.3 MB
  (void)ws_size;

  hipLaunchKernelGGL(k_transpose768, dim3(2304), dim3(256), 0, stream, w_out, wT);
  hipLaunchKernelGGL(k_gemm_qkv, dim3(18, 1136), dim3(256), 0, stream,
                     features, w_qkv, b_qkv, qkv);
  hipLaunchKernelGGL(k_attn, dim3(B_ * H_), dim3(256), 0, stream, qkv, mt, mi);
  hipLaunchKernelGGL(k_final, dim3(B_), dim3(256), 0, stream, mt, mi, wT, b_out, out);
}

// Round 2
// 1494.109 us; speedup vs baseline: 1.2723x; 1.2723x over previous
//
#include <hip/hip_runtime.h>
#include <hip/hip_bf16.h>

#define B_ 2048
#define S_ 71
#define D_ 768
#define H_ 4
#define DH_ 192
#define TD_ 2304            // 3*D
#define M_ (B_ * S_)        // 145408 = 128*1136
#define TEXT_ 35

typedef unsigned short u16;
typedef unsigned int u32;
typedef __attribute__((ext_vector_type(4))) float f32x4;
typedef __attribute__((ext_vector_type(8))) short bf16x8;

__device__ __forceinline__ u16 f2bf(float f) {
  u32 u = __float_as_uint(f);
  u32 r = (u + 0x7FFFu + ((u >> 16) & 1u)) >> 16;  // RNE
  return (u16)r;
}
__device__ __forceinline__ float bf2f(u16 x) {
  return __uint_as_float(((u32)x) << 16);
}

typedef __attribute__((address_space(1))) const unsigned int GASU;
typedef __attribute__((address_space(3))) unsigned int LASU;
__device__ __forceinline__ void gload16(const void* g, void* l) {
  __builtin_amdgcn_global_load_lds((GASU*)g, (LASU*)l, 16, 0, 0);
}

// ---------------------------------------------------------------------------
// fp32 -> bf16 elementwise, 8 elems/thread, exact grid
__global__ __launch_bounds__(256) void k_cvt_bf16(const float* __restrict__ in,
                                                  u16* __restrict__ out, int n8) {
  int idx = blockIdx.x * 256 + threadIdx.x;
  if (idx >= n8) return;
  const float4* p = (const float4*)(in + (size_t)idx * 8);
  float4 a = p[0], b = p[1];
  uint4 o;
  o.x = (u32)f2bf(a.x) | ((u32)f2bf(a.y) << 16);
  o.y = (u32)f2bf(a.z) | ((u32)f2bf(a.w) << 16);
  o.z = (u32)f2bf(b.x) | ((u32)f2bf(b.y) << 16);
  o.w = (u32)f2bf(b.z) | ((u32)f2bf(b.w) << 16);
  *(uint4*)(out + (size_t)idx * 8) = o;
}

// ---------------------------------------------------------------------------
// w_out [e][d] -> w_outT [d][e]  (768x768 fp32, tiny)
__global__ void k_transpose768(const float* __restrict__ in, float* __restrict__ out) {
  int idx = blockIdx.x * 256 + threadIdx.x;
  int e = idx / 768, d = idx % 768;
  out[(size_t)d * 768 + e] = in[idx];
}

// ---------------------------------------------------------------------------
// GEMM: C[M,2304] = A[M,768](bf16) * Bw[2304,768](bf16, n-major) with bias +
// phi(elu+1) epilogue on q,k cols. m97 structure: 128x128 tile, BK=64,
// global_load_lds width=16 into LINEAR LDS, 4 waves (64x64 each, 4x4 frags).
// XCD-bijective swizzle: each XCD owns a contiguous bm range (A panel reuse).
#define BK 64

__global__ __launch_bounds__(256) void k_gemm_qkv(
    const u16* __restrict__ A,    // [M_,768] bf16
    const u16* __restrict__ Bw,   // [2304,768] bf16 (n-major)
    const float* __restrict__ bias, // [2304]
    u16* __restrict__ C)            // [M_,2304] bf16, phi applied to cols<1536
{
  __shared__ u16 As[128 * BK];   // 16 KB, linear [row][64]
  __shared__ u16 Bs[128 * BK];   // 16 KB
  int t = threadIdx.x;
  int lane = t & 63, wid = t >> 6;

  // XCD swizzle (nwg = 20448, divisible by 8)
  int nwg = gridDim.x;
  int cpx = nwg >> 3;
  int swz = (blockIdx.x & 7) * cpx + (blockIdx.x >> 3);
  int bm = swz / 18, bn = swz % 18;

  int wm = (wid >> 1) * 64, wn = (wid & 1) * 64;
  int lr = lane & 15;
  int lk = (lane >> 4) * 8;

  f32x4 acc[4][4] = {};
  const size_t arow0 = (size_t)bm * 128;
  const size_t brow0 = (size_t)bn * 128;

  // staging geometry: per issue i, wave wid covers rows [i*32+wid*8, +8),
  // lane l -> row += l>>3, col8 = (l&7)*8. LDS dest = wave-uniform base,
  // lanes land at base + l*16B which matches linear [row][64] layout.
  int srow = (lane >> 3);
  int scol = (lane & 7) * 8;

  for (int kt = 0; kt < 768; kt += BK) {
    __syncthreads();
#pragma unroll
    for (int i = 0; i < 4; ++i) {
      int r0 = i * 32 + wid * 8;
      gload16(&A[(arow0 + r0 + srow) * 768 + kt + scol], &As[r0 * BK]);
      gload16(&Bw[(brow0 + r0 + srow) * 768 + kt + scol], &Bs[r0 * BK]);
    }
    __syncthreads();   // compiler emits s_waitcnt vmcnt(0) before s_barrier
#pragma unroll
    for (int kk = 0; kk < BK; kk += 32) {
      bf16x8 af[4], bf_[4];
#pragma unroll
      for (int m = 0; m < 4; ++m)
        af[m] = *(const bf16x8*)(&As[(wm + m * 16 + lr) * BK + kk + lk]);
#pragma unroll
      for (int n = 0; n < 4; ++n)
        bf_[n] = *(const bf16x8*)(&Bs[(wn + n * 16 + lr) * BK + kk + lk]);
#pragma unroll
      for (int m = 0; m < 4; ++m)
#pragma unroll
        for (int n = 0; n < 4; ++n)
          acc[m][n] = __builtin_amdgcn_mfma_f32_16x16x32_bf16(af[m], bf_[n], acc[m][n], 0, 0, 0);
    }
  }
  // epilogue: bias + phi on q/k columns, store bf16
  int rbase = (lane >> 4) * 4;
#pragma unroll
  for (int m = 0; m < 4; ++m) {
#pragma unroll
    for (int n = 0; n < 4; ++n) {
      int col = (int)brow0 + wn + n * 16 + lr;
      float bb = bias[col];
#pragma unroll
      for (int i = 0; i < 4; ++i) {
        size_t row = arow0 + wm + m * 16 + rbase + i;
        float v = acc[m][n][i] + bb;
        if (col < 1536) v = (v > 0.0f) ? (v + 1.0f) : __expf(v);
        C[row * TD_ + col] = f2bf(v);
      }
    }
  }
}

// ---------------------------------------------------------------------------
// Attention core, one block per (b,h). Never materializes kv[192][192].
#define ALD 196  // LDS stride for 192-wide bf16 rows

__global__ __launch_bounds__(256) void k_attn(
    const u16* __restrict__ qkv,  // [M_,2304] bf16
    float* __restrict__ mt, float* __restrict__ mi)  // [B_,768] fp32
{
  __shared__ u16 qs[S_ * ALD];
  __shared__ u16 ks2[S_ * ALD];
  __shared__ float z[DH_], wt[S_], wi[S_], qt[DH_], qi[DH_], at[S_], ai[S_];
  int t = threadIdx.x;
  int b = blockIdx.x >> 2, h = blockIdx.x & 3;
  size_t base = (size_t)b * S_ * TD_;
  int qoff = h * DH_, koff = 768 + h * DH_, voff = 1536 + h * DH_;

  for (int idx = t; idx < S_ * 48; idx += 256) {
    int s = idx / 48, c = (idx % 48) * 4;
    *(ushort4*)(&qs[s * ALD + c])  = *(const ushort4*)(&qkv[base + (size_t)s * TD_ + qoff + c]);
    *(ushort4*)(&ks2[s * ALD + c]) = *(const ushort4*)(&qkv[base + (size_t)s * TD_ + koff + c]);
  }
  __syncthreads();
  if (t < DH_) {
    float a = 0;
    for (int s = 0; s < S_; ++s) a += bf2f(ks2[s * ALD + t]);
    z[t] = a;
  }
  __syncthreads();
  if (t < S_) {
    float a = 0;
    for (int d = 0; d < DH_; ++d) a += bf2f(qs[t * ALD + d]) * z[d];
    float den = a + 1e-6f;
    wt[t] = (t < TEXT_) ? 1.0f / (35.0f * den) : 0.0f;
    wi[t] = (t >= TEXT_) ? 1.0f / (36.0f * den) : 0.0f;
  }
  __syncthreads();
  if (t < DH_) {
    float aT = 0, aI = 0;
    for (int s = 0; s < S_; ++s) {
      float qv = bf2f(qs[s * ALD + t]);
      aT += qv * wt[s]; aI += qv * wi[s];
    }
    qt[t] = aT; qi[t] = aI;
  }
  __syncthreads();
  if (t < S_) {
    float aT = 0, aI = 0;
    for (int d = 0; d < DH_; ++d) {
      float kv = bf2f(ks2[t * ALD + d]);
      aT += kv * qt[d]; aI += kv * qi[d];
    }
    at[t] = aT; ai[t] = aI;
  }
  __syncthreads();
  if (t < DH_) {
    float aT = 0, aI = 0;
    for (int s = 0; s < S_; ++s) {
      float vv = bf2f(qkv[base + (size_t)s * TD_ + voff + t]);
      aT += at[s] * vv; aI += ai[s] * vv;
    }
    mt[(size_t)b * D_ + qoff + t] = aT;
    mi[(size_t)b * D_ + qoff + t] = aI;
  }
}

// ---------------------------------------------------------------------------
// Final head: f = m @ w_out^T + b_out ; r = tanh(f) ; cosine similarity.
// G=4 batch elems per block to amortize wT reads (cuts wT L2 traffic 4x).
#define GFIN 4
__global__ __launch_bounds__(256) void k_final(
    const float* __restrict__ mt, const float* __restrict__ mi,
    const float* __restrict__ wT,   // [768,768] = w_out transposed [d][e]
    const float* __restrict__ bout, // [768]
    float* __restrict__ out)        // [B_]
{
  __shared__ float mts[GFIN][768], mis[GFIN][768];
  __shared__ float red[3][4];
  int t = threadIdx.x, b0 = blockIdx.x * GFIN;
  for (int i = t; i < GFIN * 768; i += 256) {
    int g = i / 768, d = i % 768;
    mts[g][d] = mt[(size_t)(b0 + g) * 768 + d];
    mis[g][d] = mi[(size_t)(b0 + g) * 768 + d];
  }
  __syncthreads();
  float aT[GFIN][3] = {}, aI[GFIN][3] = {};
  for (int d = 0; d < 768; ++d) {
    const float* wrow = wT + (size_t)d * 768 + t;
    float w0 = wrow[0], w1 = wrow[256], w2 = wrow[512];
#pragma unroll
    for (int g = 0; g < GFIN; ++g) {
      float m1 = mts[g][d], m2 = mis[g][d];
      aT[g][0] += m1 * w0; aT[g][1] += m1 * w1; aT[g][2] += m1 * w2;
      aI[g][0] += m2 * w0; aI[g][1] += m2 * w1; aI[g][2] += m2 * w2;
    }
  }
  int lane = t & 63, wid = t >> 6;
  for (int g = 0; g < GFIN; ++g) {
    float st = 0, si = 0, sd = 0;
#pragma unroll
    for (int j = 0; j < 3; ++j) {
      float bo = bout[t + j * 256];
      float rt = tanhf(aT[g][j] + bo);
      float ri = tanhf(aI[g][j] + bo);
      st += rt * rt; si += ri * ri; sd += rt * ri;
    }
#pragma unroll
    for (int off = 32; off >= 1; off >>= 1) {
      st += __shfl_down(st, off);
      si += __shfl_down(si, off);
      sd += __shfl_down(sd, off);
    }
    __syncthreads();
    if (lane == 0) { red[0][wid] = st; red[1][wid] = si; red[2][wid] = sd; }
    __syncthreads();
    if (t == 0) {
      float S1 = red[0][0] + red[0][1] + red[0][2] + red[0][3];
      float S2 = red[1][0] + red[1][1] + red[1][2] + red[1][3];
      float S3 = red[2][0] + red[2][1] + red[2][2] + red[2][3];
      out[b0 + g] = S3 / (fmaxf(sqrtf(S1), 1e-8f) * fmaxf(sqrtf(S2), 1e-8f));
    }
  }
}

// ---------------------------------------------------------------------------
extern "C" void kernel_launch(void* const* d_in, const int* in_sizes, int n_in,
                              void* d_out, int out_size, void* d_ws, size_t ws_size,
                              hipStream_t stream) {
  const float* features = (const float*)d_in[0];
  // d_in[1] = attention_mask (unused by forward)
  const float* w_qkv = (const float*)d_in[2];
  const float* b_qkv = (const float*)d_in[3];
  const float* w_out = (const float*)d_in[4];
  const float* b_out = (const float*)d_in[5];
  float* out = (float*)d_out;

  char* ws = (char*)d_ws;
  size_t off = 0;
  auto alloc = [&](size_t bytes) {
    void* p = ws + off;
    off += (bytes + 255) & ~(size_t)255;
    return p;
  };
  u16* qkv  = (u16*)alloc((size_t)M_ * TD_ * 2);   // 670 MB
  u16* Abf  = (u16*)alloc((size_t)M_ * D_ * 2);    // 223 MB
  u16* Wbf  = (u16*)alloc((size_t)TD_ * D_ * 2);   // 3.5 MB
  float* wT = (float*)alloc((size_t)D_ * D_ * 4);  // 2.4 MB
  float* mt = (float*)alloc((size_t)B_ * D_ * 4);  // 6.3 MB
  float* mi = (float*)alloc((size_t)B_ * D_ * 4);  // 6.3 MB
  (void)ws_size;

  // converts + transpose
  hipLaunchKernelGGL(k_cvt_bf16, dim3((M_ * D_ / 8 + 255) / 256), dim3(256), 0, stream,
                     features, Abf, M_ * D_ / 8);
  hipLaunchKernelGGL(k_cvt_bf16, dim3((TD_ * D_ / 8 + 255) / 256), dim3(256), 0, stream,
                     w_qkv, Wbf, TD_ * D_ / 8);
  hipLaunchKernelGGL(k_transpose768, dim3(2304), dim3(256), 0, stream, w_out, wT);

  hipLaunchKernelGGL(k_gemm_qkv, dim3(18 * 1136), dim3(256), 0, stream,
                     Abf, Wbf, b_qkv, qkv);
  hipLaunchKernelGGL(k_attn, dim3(B_ * H_), dim3(256), 0, stream, qkv, mt, mi);
  hipLaunchKernelGGL(k_final, dim3(B_ / GFIN), dim3(256), 0, stream, mt, mi, wT, b_out, out);
}

// Round 3
// 1162.176 us; speedup vs baseline: 1.6357x; 1.2856x over previous
//
#include <hip/hip_runtime.h>
#include <hip/hip_bf16.h>

#define B_ 2048
#define S_ 71
#define D_ 768
#define H_ 4
#define DH_ 192
#define TD_ 2304            // 3*D
#define M_ (B_ * S_)        // 145408 = 568*256
#define TEXT_ 35
#define NKT 12              // 768 / 64 K-tiles

typedef unsigned short u16;
typedef unsigned int u32;
typedef __attribute__((ext_vector_type(4))) float f32x4;
typedef __attribute__((ext_vector_type(8))) short bf16x8;

__device__ __forceinline__ u16 f2bf(float f) {
  u32 u = __float_as_uint(f);
  u32 r = (u + 0x7FFFu + ((u >> 16) & 1u)) >> 16;  // RNE
  return (u16)r;
}
__device__ __forceinline__ float bf2f(u16 x) {
  return __uint_as_float(((u32)x) << 16);
}

typedef __attribute__((address_space(1))) const unsigned int GASU;
typedef __attribute__((address_space(3))) unsigned int LASU;
__device__ __forceinline__ void gload16(const void* g, void* l) {
  __builtin_amdgcn_global_load_lds((GASU*)g, (LASU*)l, 16, 0, 0);
}

#define PHASE_BAR() do { __builtin_amdgcn_s_barrier(); asm volatile("" ::: "memory"); } while (0)

// ---------------------------------------------------------------------------
// fp32 -> bf16 elementwise, 8 elems/thread, exact grid
__global__ __launch_bounds__(256) void k_cvt_bf16(const float* __restrict__ in,
                                                  u16* __restrict__ out, int n8) {
  int idx = blockIdx.x * 256 + threadIdx.x;
  if (idx >= n8) return;
  const float4* p = (const float4*)(in + (size_t)idx * 8);
  float4 a = p[0], b = p[1];
  uint4 o;
  o.x = (u32)f2bf(a.x) | ((u32)f2bf(a.y) << 16);
  o.y = (u32)f2bf(a.z) | ((u32)f2bf(a.w) << 16);
  o.z = (u32)f2bf(b.x) | ((u32)f2bf(b.y) << 16);
  o.w = (u32)f2bf(b.z) | ((u32)f2bf(b.w) << 16);
  *(uint4*)(out + (size_t)idx * 8) = o;
}

// ---------------------------------------------------------------------------
// w_out [e][d] -> w_outT [d][e]  (768x768 fp32, tiny)
__global__ void k_transpose768(const float* __restrict__ in, float* __restrict__ out) {
  int idx = blockIdx.x * 256 + threadIdx.x;
  int e = idx / 768, d = idx % 768;
  out[(size_t)d * 768 + e] = in[idx];
}

// ---------------------------------------------------------------------------
// GEMM: C[M,2304] = A[M,768](bf16) * Bw[2304,768](bf16 n-major), bias + phi
// epilogue. 256x256 tile, BK=64, 8 waves (2Mx4N), 512 thr, 128 KiB LDS
// (2 K-tile dbuf). Deep pipeline: K-tile T+1's 8 gload_lds issued at top of
// iter T into the buffer freed at end of iter T-1; single vmcnt(0) sits 4
// compute phases after issue. chunk^(row&7) 16B XOR swizzle on source+read.
__global__ __launch_bounds__(512, 2) void k_gemm_qkv(
    const u16* __restrict__ Abf,  // [M_,768] bf16
    const u16* __restrict__ Bw,   // [2304,768] bf16 (n-major)
    const float* __restrict__ bias, // [2304]
    u16* __restrict__ C)            // [M_,2304] bf16, phi on cols<1536
{
  // layout (u16 units): buf*32768 + op*16384 + half*8192 ; half = [128][64]
  __shared__ u16 sm[65536];   // 128 KiB
  int t = threadIdx.x;
  int lane = t & 63, wid = t >> 6;
  int wr = wid >> 2, wc = wid & 3;     // 2 x 4 wave grid
  int lr = lane & 15;
  int g4 = lane >> 4;                  // 0..3 (K granule within kk)

  // XCD-bijective swizzle: nwg = 5112 = 8 * 639; bn inner -> A-panel L2 reuse
  int swz = (blockIdx.x & 7) * 639 + (blockIdx.x >> 3);
  int bm = swz / 9, bn = swz % 9;
  const size_t arow0 = (size_t)bm * 256;
  const int bcol0 = bn * 256;

  // ---- staging descriptors (loop-invariant) --------------------------------
  const u16* gsrc[8];
  int ldst[8];                         // u16 offset within buffer
#pragma unroll
  for (int j = 0; j < 8; ++j) {
    int op = j >> 2, half = (j >> 1) & 1, which = j & 1;
    int ci = which * 512 + t;          // 0..1023 chunk index in half-tile
    int row = ci >> 3, k = ci & 7;
    int kg = k ^ (row & 7);            // inverse swizzle on SOURCE
    gsrc[j] = (op == 0 ? Abf + (arow0 + half * 128 + row) * 768
                       : Bw + (size_t)(bcol0 + half * 128 + row) * 768) + kg * 8;
    ldst[j] = op * 16384 + half * 8192 + (which * 512 + wid * 64) * 8; // wave-uniform base
  }

  // ---- fragment read offsets (swizzled) ------------------------------------
  int gx0 = g4 ^ (lr & 7);             // kk=0 granule; kk=1 -> gx0^4
  int abase = wr * 8192 + lr * 64;                      // + mi*1024 + gsw*8
  int bbase = 16384 + (wc >> 1) * 8192 + (wc & 1) * 4096 + lr * 64; // + ni*1024 + gsw*8

  f32x4 acc[8][4] = {};
  bf16x8 a_[4][2], b0_[2][2], b1_[2][2];

#define RDA(bufb, mi, gsw) (*(const bf16x8*)(&sm[(bufb) + abase + (mi) * 1024 + (gsw) * 8]))
#define RDB(bufb, ni, gsw) (*(const bf16x8*)(&sm[(bufb) + bbase + (ni) * 1024 + (gsw) * 8]))

  // prologue: stage K-tile 0 into buf0
#pragma unroll
  for (int j = 0; j < 8; ++j) gload16(gsrc[j], &sm[ldst[j]]);
  asm volatile("s_waitcnt vmcnt(0)" ::: "memory");
  __builtin_amdgcn_s_barrier();
  asm volatile("" ::: "memory");

#pragma unroll 2
  for (int T = 0; T < NKT; ++T) {
    int bufb = (T & 1) * 32768;
    int nbufb = 32768 - bufb;
    if (T < NKT - 1) {                 // issue next K-tile early (WAR-safe)
#pragma unroll
      for (int j = 0; j < 8; ++j)
        gload16(gsrc[j] + (size_t)(T + 1) * 64, &sm[nbufb + ldst[j]]);
    }
    // ---- phase 1: quadrant (mh0, nh0) ----
#pragma unroll
    for (int mi = 0; mi < 4; ++mi) { a_[mi][0] = RDA(bufb, mi, gx0); a_[mi][1] = RDA(bufb, mi, gx0 ^ 4); }
#pragma unroll
    for (int ni = 0; ni < 2; ++ni) { b0_[ni][0] = RDB(bufb, ni, gx0); b0_[ni][1] = RDB(bufb, ni, gx0 ^ 4); }
    __builtin_amdgcn_s_setprio(1);
#pragma unroll
    for (int mi = 0; mi < 4; ++mi)
#pragma unroll
      for (int ni = 0; ni < 2; ++ni)
#pragma unroll
        for (int kk = 0; kk < 2; ++kk)
          acc[mi][ni] = __builtin_amdgcn_mfma_f32_16x16x32_bf16(a_[mi][kk], b0_[ni][kk], acc[mi][ni], 0, 0, 0);
    __builtin_amdgcn_s_setprio(0);
    PHASE_BAR();
    // ---- phase 2: (mh0, nh1) ----
#pragma unroll
    for (int ni = 0; ni < 2; ++ni) { b1_[ni][0] = RDB(bufb, ni + 2, gx0); b1_[ni][1] = RDB(bufb, ni + 2, gx0 ^ 4); }
    __builtin_amdgcn_s_setprio(1);
#pragma unroll
    for (int mi = 0; mi < 4; ++mi)
#pragma unroll
      for (int ni = 0; ni < 2; ++ni)
#pragma unroll
        for (int kk = 0; kk < 2; ++kk)
          acc[mi][ni + 2] = __builtin_amdgcn_mfma_f32_16x16x32_bf16(a_[mi][kk], b1_[ni][kk], acc[mi][ni + 2], 0, 0, 0);
    __builtin_amdgcn_s_setprio(0);
    PHASE_BAR();
    // ---- phase 3: (mh1, nh1) ----
#pragma unroll
    for (int mi = 0; mi < 4; ++mi) { a_[mi][0] = RDA(bufb, mi + 4, gx0); a_[mi][1] = RDA(bufb, mi + 4, gx0 ^ 4); }
    __builtin_amdgcn_s_setprio(1);
#pragma unroll
    for (int mi = 0; mi < 4; ++mi)
#pragma unroll
      for (int ni = 0; ni < 2; ++ni)
#pragma unroll
        for (int kk = 0; kk < 2; ++kk)
          acc[mi + 4][ni + 2] = __builtin_amdgcn_mfma_f32_16x16x32_bf16(a_[mi][kk], b1_[ni][kk], acc[mi + 4][ni + 2], 0, 0, 0);
    __builtin_amdgcn_s_setprio(0);
    PHASE_BAR();
    // ---- phase 4: (mh1, nh0) — pure MFMA, loads keep landing ----
    __builtin_amdgcn_s_setprio(1);
#pragma unroll
    for (int mi = 0; mi < 4; ++mi)
#pragma unroll
      for (int ni = 0; ni < 2; ++ni)
#pragma unroll
        for (int kk = 0; kk < 2; ++kk)
          acc[mi + 4][ni] = __builtin_amdgcn_mfma_f32_16x16x32_bf16(a_[mi][kk], b0_[ni][kk], acc[mi + 4][ni], 0, 0, 0);
    __builtin_amdgcn_s_setprio(0);
    // end of iter: next K-tile must be landed; old buffer reads all done
    asm volatile("s_waitcnt vmcnt(0)" ::: "memory");
    __builtin_amdgcn_s_barrier();
    asm volatile("" ::: "memory");
  }

  // epilogue: bias + phi, direct bf16 stores
  int rb = g4 * 4;
#pragma unroll
  for (int mi = 0; mi < 8; ++mi) {
#pragma unroll
    for (int ni = 0; ni < 4; ++ni) {
      int col = bcol0 + wc * 64 + ni * 16 + lr;
      float bb = bias[col];
#pragma unroll
      for (int i = 0; i < 4; ++i) {
        size_t row = arow0 + wr * 128 + mi * 16 + rb + i;
        float v = acc[mi][ni][i] + bb;
        if (col < 1536) v = (v > 0.0f) ? (v + 1.0f) : __expf(v);
        C[row * TD_ + col] = f2bf(v);
      }
    }
  }
#undef RDA
#undef RDB
}

// ---------------------------------------------------------------------------
// Attention core, one block per (b,h). Never materializes kv[192][192].
#define ALD 196  // LDS stride for 192-wide bf16 rows

__global__ __launch_bounds__(256) void k_attn(
    const u16* __restrict__ qkv,  // [M_,2304] bf16
    float* __restrict__ mt, float* __restrict__ mi)  // [B_,768] fp32
{
  __shared__ u16 qs[S_ * ALD];
  __shared__ u16 ks2[S_ * ALD];
  __shared__ float z[DH_], wt[S_], wi[S_], qt[DH_], qi[DH_], at[S_], ai[S_];
  int t = threadIdx.x;
  int b = blockIdx.x >> 2, h = blockIdx.x & 3;
  size_t base = (size_t)b * S_ * TD_;
  int qoff = h * DH_, koff = 768 + h * DH_, voff = 1536 + h * DH_;

  for (int idx = t; idx < S_ * 48; idx += 256) {
    int s = idx / 48, c = (idx % 48) * 4;
    *(ushort4*)(&qs[s * ALD + c])  = *(const ushort4*)(&qkv[base + (size_t)s * TD_ + qoff + c]);
    *(ushort4*)(&ks2[s * ALD + c]) = *(const ushort4*)(&qkv[base + (size_t)s * TD_ + koff + c]);
  }
  __syncthreads();
  if (t < DH_) {
    float a = 0;
    for (int s = 0; s < S_; ++s) a += bf2f(ks2[s * ALD + t]);
    z[t] = a;
  }
  __syncthreads();
  if (t < S_) {
    float a = 0;
    for (int d = 0; d < DH_; ++d) a += bf2f(qs[t * ALD + d]) * z[d];
    float den = a + 1e-6f;
    wt[t] = (t < TEXT_) ? 1.0f / (35.0f * den) : 0.0f;
    wi[t] = (t >= TEXT_) ? 1.0f / (36.0f * den) : 0.0f;
  }
  __syncthreads();
  if (t < DH_) {
    float aT = 0, aI = 0;
    for (int s = 0; s < S_; ++s) {
      float qv = bf2f(qs[s * ALD + t]);
      aT += qv * wt[s]; aI += qv * wi[s];
    }
    qt[t] = aT; qi[t] = aI;
  }
  __syncthreads();
  if (t < S_) {
    float aT = 0, aI = 0;
    for (int d = 0; d < DH_; ++d) {
      float kv = bf2f(ks2[t * ALD + d]);
      aT += kv * qt[d]; aI += kv * qi[d];
    }
    at[t] = aT; ai[t] = aI;
  }
  __syncthreads();
  if (t < DH_) {
    float aT = 0, aI = 0;
    for (int s = 0; s < S_; ++s) {
      float vv = bf2f(qkv[base + (size_t)s * TD_ + voff + t]);
      aT += at[s] * vv; aI += ai[s] * vv;
    }
    mt[(size_t)b * D_ + qoff + t] = aT;
    mi[(size_t)b * D_ + qoff + t] = aI;
  }
}

// ---------------------------------------------------------------------------
// Final head: f = m @ w_out^T + b_out ; r = tanh(f) ; cosine similarity.
#define GFIN 4
__global__ __launch_bounds__(256) void k_final(
    const float* __restrict__ mt, const float* __restrict__ mi,
    const float* __restrict__ wT,   // [768,768] = w_out transposed [d][e]
    const float* __restrict__ bout, // [768]
    float* __restrict__ out)        // [B_]
{
  __shared__ float mts[GFIN][768], mis[GFIN][768];
  __shared__ float red[3][4];
  int t = threadIdx.x, b0 = blockIdx.x * GFIN;
  for (int i = t; i < GFIN * 768; i += 256) {
    int g = i / 768, d = i % 768;
    mts[g][d] = mt[(size_t)(b0 + g) * 768 + d];
    mis[g][d] = mi[(size_t)(b0 + g) * 768 + d];
  }
  __syncthreads();
  float aT[GFIN][3] = {}, aI[GFIN][3] = {};
  for (int d = 0; d < 768; ++d) {
    const float* wrow = wT + (size_t)d * 768 + t;
    float w0 = wrow[0], w1 = wrow[256], w2 = wrow[512];
#pragma unroll
    for (int g = 0; g < GFIN; ++g) {
      float m1 = mts[g][d], m2 = mis[g][d];
      aT[g][0] += m1 * w0; aT[g][1] += m1 * w1; aT[g][2] += m1 * w2;
      aI[g][0] += m2 * w0; aI[g][1] += m2 * w1; aI[g][2] += m2 * w2;
    }
  }
  int lane = t & 63, wid = t >> 6;
  for (int g = 0; g < GFIN; ++g) {
    float st = 0, si = 0, sd = 0;
#pragma unroll
    for (int j = 0; j < 3; ++j) {
      float bo = bout[t + j * 256];
      float rt = tanhf(aT[g][j] + bo);
      float ri = tanhf(aI[g][j] + bo);
      st += rt * rt; si += ri * ri; sd += rt * ri;
    }
#pragma unroll
    for (int off = 32; off >= 1; off >>= 1) {
      st += __shfl_down(st, off);
      si += __shfl_down(si, off);
      sd += __shfl_down(sd, off);
    }
    __syncthreads();
    if (lane == 0) { red[0][wid] = st; red[1][wid] = si; red[2][wid] = sd; }
    __syncthreads();
    if (t == 0) {
      float S1 = red[0][0] + red[0][1] + red[0][2] + red[0][3];
      float S2 = red[1][0] + red[1][1] + red[1][2] + red[1][3];
      float S3 = red[2][0] + red[2][1] + red[2][2] + red[2][3];
      out[b0 + g] = S3 / (fmaxf(sqrtf(S1), 1e-8f) * fmaxf(sqrtf(S2), 1e-8f));
    }
  }
}

// ---------------------------------------------------------------------------
extern "C" void kernel_launch(void* const* d_in, const int* in_sizes, int n_in,
                              void* d_out, int out_size, void* d_ws, size_t ws_size,
                              hipStream_t stream) {
  const float* features = (const float*)d_in[0];
  // d_in[1] = attention_mask (unused by forward)
  const float* w_qkv = (const float*)d_in[2];
  const float* b_qkv = (const float*)d_in[3];
  const float* w_out = (const float*)d_in[4];
  const float* b_out = (const float*)d_in[5];
  float* out = (float*)d_out;

  char* ws = (char*)d_ws;
  size_t off = 0;
  auto alloc = [&](size_t bytes) {
    void* p = ws + off;
    off += (bytes + 255) & ~(size_t)255;
    return p;
  };
  u16* qkv  = (u16*)alloc((size_t)M_ * TD_ * 2);   // 670 MB
  u16* Abf  = (u16*)alloc((size_t)M_ * D_ * 2);    // 223 MB
  u16* Wbf  = (u16*)alloc((size_t)TD_ * D_ * 2);   // 3.5 MB
  float* wT = (float*)alloc((size_t)D_ * D_ * 4);  // 2.4 MB
  float* mt = (float*)alloc((size_t)B_ * D_ * 4);  // 6.3 MB
  float* mi = (float*)alloc((size_t)B_ * D_ * 4);  // 6.3 MB
  (void)ws_size;

  hipLaunchKernelGGL(k_cvt_bf16, dim3((M_ * D_ / 8 + 255) / 256), dim3(256), 0, stream,
                     features, Abf, M_ * D_ / 8);
  hipLaunchKernelGGL(k_cvt_bf16, dim3((TD_ * D_ / 8 + 255) / 256), dim3(256), 0, stream,
                     w_qkv, Wbf, TD_ * D_ / 8);
  hipLaunchKernelGGL(k_transpose768, dim3(2304), dim3(256), 0, stream, w_out, wT);

  hipLaunchKernelGGL(k_gemm_qkv, dim3(568 * 9), dim3(512), 0, stream,
                     Abf, Wbf, b_qkv, qkv);
  hipLaunchKernelGGL(k_attn, dim3(B_ * H_), dim3(256), 0, stream, qkv, mt, mi);
  hipLaunchKernelGGL(k_final, dim3(B_ / GFIN), dim3(256), 0, stream, mt, mi, wT, b_out, out);
}